// Round 6
// baseline (45.883 us; speedup 1.0000x reference)
//
#include <hip/hip_runtime.h>

#define TT 16384
#define DD 2048
#define EE 64

typedef __attribute__((ext_vector_type(8))) short bf16x8;
typedef __attribute__((ext_vector_type(8))) unsigned short ushort8;
typedef __attribute__((ext_vector_type(4))) float f32x4;
typedef __attribute__((ext_vector_type(16))) float f32x16;

__device__ __forceinline__ unsigned short bf16_rne(float f) {
    unsigned u = __float_as_uint(f);
    return (unsigned short)((u + 0x7FFFu + ((u >> 16) & 1u)) >> 16);
}
__device__ __forceinline__ float bf16_f32(unsigned short h) {
    return __uint_as_float(((unsigned)h) << 16);
}
__device__ __forceinline__ unsigned cvt_pk(float lo, float hi) {
    unsigned r;
    asm("v_cvt_pk_bf16_f32 %0, %1, %2" : "=v"(r) : "v"(lo), "v"(hi));
    return r;  // low16 = bf16(lo), high16 = bf16(hi)
}
__device__ __forceinline__ bf16x8 pack4(unsigned a, unsigned b, unsigned c, unsigned d) {
    union { unsigned u[4]; bf16x8 v; } t;
    t.u[0] = a; t.u[1] = b; t.u[2] = c; t.u[3] = d;
    return t.v;
}
__device__ __forceinline__ void gload16(void* lds, const void* g) {
    __builtin_amdgcn_global_load_lds(
        (const __attribute__((address_space(1))) unsigned int*)g,
        (__attribute__((address_space(3))) unsigned int*)lds, 16, 0, 0);
}

// ---------------------------------------------------------------------------
// W [2048][64] f32 -> wpack: 32x32x16 A-fragments in exact load order.
// frag_id = (t*2 + m)*2 + h   (t = 16-k chunk 0..127, m = expert half, h = hi/lo)
// element: wpack[frag_id*512 + lane*8 + j] = bf16 of
//          wg[(t*16 + (lane>>5)*8 + j)*64 + m*32 + (lane&31)]
__global__ __launch_bounds__(256)
void wconv(const float* __restrict__ wg, unsigned short* __restrict__ wpack) {
    const int g = (int)blockIdx.x * 256 + threadIdx.x;  // 32768 threads
    const int t = g >> 8, m = (g >> 7) & 1, h = (g >> 6) & 1, lane = g & 63;
    const int e = m * 32 + (lane & 31);
    const int ks = t * 16 + (lane >> 5) * 8;
    ushort8 v;
#pragma unroll
    for (int j = 0; j < 8; ++j) {
        const float f = wg[(size_t)(ks + j) * EE + e];
        const unsigned short hi = bf16_rne(f);
        v[j] = h ? bf16_rne(f - bf16_f32(hi)) : hi;
    }
    *(ushort8*)(wpack + (size_t)g * 8) = v;
}

// ---------------------------------------------------------------------------
// Fused gate GEMM (32x32x16 bf16x3) + biased top-2 + softmax + bins.
// Block = 512 thr = 8 waves, ALL on the same 32 tokens; wave q owns the
// K-eighth [q*256, q*256+256), 8 steps x 32 k.  Grid 512 = 2 blocks/CU.
// x: global_load_lds 2-ring (32 KB/step), source-side chunk XOR swizzle.
// W: single-slot register frags from wpack (L2-hot), loaded BEFORE stage so
// the compiler's W-reg wait never drains the x-stage queue.  vmcnt(12).
// Frag maps: A row=lane&31(expert), k=(lane>>5)*8+j; B col=lane&31(token);
//            D col=lane&31, row e=(reg&3)+8*(reg>>2)+4*(lane>>5) (+m*32).
__global__ __launch_bounds__(512, 4)
void gate_fused(const float* __restrict__ x, const unsigned short* __restrict__ wpack,
                const float* __restrict__ loads, float* __restrict__ out,
                float* __restrict__ binpart) {
    __shared__ __align__(16) float arena[16384];  // 64 KB: 2 ring bufs x 32 KB
    __shared__ float bins[64];

    const int tid = threadIdx.x, lane = tid & 63, q = tid >> 6;
    const int tb = (int)blockIdx.x;
    const int tok = lane & 31, hi5 = lane >> 5;

    f32x16 acc[2];
#pragma unroll
    for (int m = 0; m < 2; ++m)
#pragma unroll
        for (int r = 0; r < 16; ++r) acc[m][r] = 0.0f;

    // stage step s of this wave's K-eighth for all 32 tokens (4 KB/wave)
    auto stage_x = [&](int s, float* rb) {
#pragma unroll
        for (int i = 0; i < 4; ++i) {
            const int row = i * 8 + (lane >> 3);
            const int c = (lane & 7) ^ (lane >> 3);  // source-side chunk swizzle
            gload16(rb + q * 1024 + i * 256,
                    x + (size_t)(tb * 32 + row) * DD + q * 256 + s * 32 + c * 4);
        }
    };
    // 8 W frags for step s: [ts*4 + m*2 + h], each 16 B/lane coalesced
    bf16x8 W[8];
    auto loadW = [&](int s) {
        const unsigned short* base =
            wpack + (size_t)((q * 16 + s * 2) * 4) * 512 + lane * 8;
#pragma unroll
        for (int f = 0; f < 8; ++f)
            W[f] = *(const bf16x8*)(base + (size_t)f * 512);
    };
    auto compute = [&](const float* rb) {
        const float* xq = rb + q * 1024 + tok * 32;
        const int key = tok & 7;
#pragma unroll
        for (int ts = 0; ts < 2; ++ts) {
            const int c0 = ts * 4 + hi5 * 2;
            const f32x4 va = *(const f32x4*)(xq + ((c0) ^ key) * 4);
            const f32x4 vb = *(const f32x4*)(xq + ((c0 + 1) ^ key) * 4);
            const float cf[8] = {va.x, va.y, va.z, va.w, vb.x, vb.y, vb.z, vb.w};
            unsigned ph[4], pl[4];
#pragma unroll
            for (int j = 0; j < 4; ++j) {
                ph[j] = cvt_pk(cf[2 * j], cf[2 * j + 1]);
                const float h0 = __uint_as_float(ph[j] << 16);
                const float h1 = __uint_as_float(ph[j] & 0xFFFF0000u);
                pl[j] = cvt_pk(cf[2 * j] - h0, cf[2 * j + 1] - h1);
            }
            const bf16x8 bhi = pack4(ph[0], ph[1], ph[2], ph[3]);
            const bf16x8 blo = pack4(pl[0], pl[1], pl[2], pl[3]);
#pragma unroll
            for (int m = 0; m < 2; ++m) {
                acc[m] = __builtin_amdgcn_mfma_f32_32x32x16_bf16(
                    W[ts * 4 + m * 2], bhi, acc[m], 0, 0, 0);
                acc[m] = __builtin_amdgcn_mfma_f32_32x32x16_bf16(
                    W[ts * 4 + m * 2], blo, acc[m], 0, 0, 0);
                acc[m] = __builtin_amdgcn_mfma_f32_32x32x16_bf16(
                    W[ts * 4 + m * 2 + 1], bhi, acc[m], 0, 0, 0);
            }
        }
    };

    // prologue: stage(0), loadW(0), stage(1)  -> drain stage(0) via vmcnt(12)
    stage_x(0, arena);
    loadW(0);
    stage_x(1, arena + 8192);
    asm volatile("s_waitcnt vmcnt(12)" ::: "memory");
    __builtin_amdgcn_s_barrier();

#pragma unroll 1
    for (int s = 0; s < 8; ++s) {
        compute((s & 1) ? arena + 8192 : arena);
        __builtin_amdgcn_s_barrier();              // all readers of ring[s&1] done
        if (s < 6) {
            loadW(s + 1);                          // W first: reg-wait won't drain stage
            stage_x(s + 2, (s & 1) ? arena + 8192 : arena);
            asm volatile("s_waitcnt vmcnt(12)" ::: "memory");  // drain stage(s+1)
            __builtin_amdgcn_s_barrier();
        } else if (s == 6) {
            loadW(7);
            asm volatile("s_waitcnt vmcnt(8)" ::: "memory");   // drain stage(7)
            __builtin_amdgcn_s_barrier();
        }
    }

    // ---- deterministic 8-way K-split reduce through arena overlay --------
    // overlay[qq][lane][36] : stride 36 floats spreads f32x4 writes over banks
    if (q != 0) {
        float* ov = arena + (size_t)(q - 1) * 2304 + lane * 36;
#pragma unroll
        for (int m = 0; m < 2; ++m)
#pragma unroll
            for (int p = 0; p < 4; ++p) {
                const f32x4 t_ = {acc[m][p * 4], acc[m][p * 4 + 1],
                                  acc[m][p * 4 + 2], acc[m][p * 4 + 3]};
                *(f32x4*)(ov + m * 16 + p * 4) = t_;
            }
    }
    __syncthreads();
    if (q != 0) return;

#pragma unroll 1
    for (int qq = 0; qq < 7; ++qq) {
        const float* ov = arena + (size_t)qq * 2304 + lane * 36;
#pragma unroll
        for (int m = 0; m < 2; ++m)
#pragma unroll
            for (int p = 0; p < 4; ++p) {
                const f32x4 t_ = *(const f32x4*)(ov + m * 16 + p * 4);
#pragma unroll
                for (int j = 0; j < 4; ++j) acc[m][p * 4 + j] += t_[j];
            }
    }

    // ---- top-2 (biased): lane holds e = m*32 + (reg&3) + 8*(reg>>2) + 4*hi5
    float v1 = -3.4e38f, u1 = 0.0f, v2 = -3.4e38f, u2 = 0.0f;
    int i1 = 0x7fffffff, i2 = 0x7fffffff;
#pragma unroll
    for (int m = 0; m < 2; ++m)
#pragma unroll
        for (int r = 0; r < 16; ++r) {
            const int e = m * 32 + (r & 3) + 8 * (r >> 2) + 4 * hi5;
            const float u = acc[m][r];
            const float b = u - (loads[e] - 0.015625f) * 2.0f;
            if ((b > v1) || (b == v1 && e < i1)) {
                v2 = v1; u2 = u1; i2 = i1;
                v1 = b;  u1 = u;  i1 = e;
            } else if ((b > v2) || (b == v2 && e < i2)) {
                v2 = b; u2 = u; i2 = e;
            }
        }
    {   // merge lane <-> lane+32 (same token, other expert rows)
        const float ov1 = __shfl_xor(v1, 32), ou1 = __shfl_xor(u1, 32);
        const float ov2 = __shfl_xor(v2, 32), ou2 = __shfl_xor(u2, 32);
        const int oi1 = __shfl_xor(i1, 32), oi2 = __shfl_xor(i2, 32);
        if ((ov1 > v1) || (ov1 == v1 && oi1 < i1)) {
            if ((v1 > ov2) || (v1 == ov2 && i1 < oi2)) { v2 = v1; u2 = u1; i2 = i1; }
            else                                        { v2 = ov2; u2 = ou2; i2 = oi2; }
            v1 = ov1; u1 = ou1; i1 = oi1;
        } else if ((ov1 > v2) || (ov1 == v2 && oi1 < i2)) {
            v2 = ov1; u2 = ou1; i2 = oi1;
        }
    }

    bins[lane] = 0.0f;
    if (lane < 32) {
        const int tg = tb * 32 + tok;
        const float mx = fmaxf(u1, u2);
        const float e1 = __expf(u1 - mx), e2 = __expf(u2 - mx);
        const float w1 = e1 / (e1 + e2), w2 = e2 / (e1 + e2);
        *(float2*)(out + 2 * tg) = make_float2(w1, w2);
        *(float2*)(out + 2 * TT + 2 * tg) = make_float2((float)i1, (float)i2);
        atomicAdd(&bins[i1], w1);
        atomicAdd(&bins[i2], w2);
    }
    binpart[(size_t)tb * 64 + lane] = bins[lane];
}

// ---------------------------------------------------------------------------
// Deterministic two-stage bin reduction (512 rows) + EMA.
__global__ __launch_bounds__(256)
void finalize1(const float* __restrict__ binpart, float* __restrict__ binmid) {
    __shared__ float p[4][64];
    const int e = threadIdx.x & 63, sub = threadIdx.x >> 6;
    float s = 0.0f;
#pragma unroll
    for (int r = 0; r < 8; ++r)
        s += binpart[(size_t)(((int)blockIdx.x * 4 + sub) * 8 + r) * 64 + e];
    p[sub][e] = s;
    __syncthreads();
    if (sub == 0)
        binmid[(int)blockIdx.x * 64 + e] = ((p[0][e] + p[1][e]) + p[2][e]) + p[3][e];
}

__global__ __launch_bounds__(64)
void finalize2(const float* __restrict__ binmid, const float* __restrict__ loads,
               float* __restrict__ out) {
    const int e = threadIdx.x;
    float s = 0.0f;
#pragma unroll
    for (int j = 0; j < 16; ++j) s += binmid[j * 64 + e];
    out[4 * TT + e] = 0.9f * loads[e] + 0.1f * (s * (1.0f / 16384.0f));
}

// ---------------------------------------------------------------------------
extern "C" void kernel_launch(void* const* d_in, const int* in_sizes, int n_in,
                              void* d_out, int out_size, void* d_ws, size_t ws_size,
                              hipStream_t stream) {
    const float* x = (const float*)d_in[0];      // [16384, 2048]
    const float* wg = (const float*)d_in[1];     // [2048, 64]
    const float* loads = (const float*)d_in[2];  // [64]
    float* out = (float*)d_out;

    unsigned short* wpack = (unsigned short*)d_ws;               // 512 KB
    float* binpart = (float*)(wpack + (size_t)64 * 8 * 64 * 8);  // [512][64]
    float* binmid = binpart + 512 * 64;                          // [16][64]

    hipLaunchKernelGGL(wconv, dim3(128), dim3(256), 0, stream, wg, wpack);
    hipLaunchKernelGGL(gate_fused, dim3(512), dim3(512), 0, stream,
                       x, wpack, loads, out, binpart);
    hipLaunchKernelGGL(finalize1, dim3(16), dim3(256), 0, stream, binpart, binmid);
    hipLaunchKernelGGL(finalize2, dim3(1), dim3(64), 0, stream, binmid, loads, out);
}